// Round 10
// baseline (62.108 us; speedup 1.0000x reference)
//
#include <hip/hip_runtime.h>
#include <math.h>

#define LOG2E 1.4426950408889634f
#define NSLOT 256          // LDS window: atoms [key_base, key_base+256)
#define EPT   4            // edges per thread (best TLP point: R4/R8/R9 sweep)
#define EPB   (256 * EPT)  // 1024 edges per block

// clang native vectors (needed for __builtin_nontemporal_load)
typedef __attribute__((ext_vector_type(4))) float f4v;
typedef __attribute__((ext_vector_type(4))) int   i4v;

// Fully fused ZBL repulsion (R7 structure, verified):
//   consts   : recomputed uniformly from the 9 scalar inputs (cheap).
//   i-side   : za window staged in LDS from coalesced z/amask loads
//              (idx_i sorted => 1024-edge block spans ~16 atoms). i-factor
//              0.5*z_i*amask_i deferred to the sweep (exact distributivity).
//   j-side   : gather z[j] (4B, CACHED - the only data with L2 reuse).
//   streams  : idx_i/idx_j/disp/bmask loaded NON-TEMPORAL (nt) - zero reuse,
//              so don't let 19MB/XCD of stream traffic evict the 400KB
//              z-table from L2 (gathers depend on it staying resident).
//   reduce   : in-register run merge -> LDS atomics keyed rel. key_base ->
//              barrier -> sweep emits <=1 global atomic per touched atom.
//   Out-of-window keys fall back to guarded global atomics, so correctness
//   never depends on idx_i being sorted.
__global__ __launch_bounds__(256) void zbl_fused_kernel(
    const float* __restrict__ z, const float* __restrict__ amask,
    const float* __restrict__ disp, const int* __restrict__ idx_i,
    const int* __restrict__ idx_j, const float* __restrict__ bmask,
    const float* __restrict__ a_coef, const float* __restrict__ a_exp,
    const float* __restrict__ phi_c, const float* __restrict__ phi_e,
    float* __restrict__ out, int n_edges, int n_atoms) {
  __shared__ float za_s[NSLOT];
  __shared__ float acc[NSLOT];
  const int t = threadIdx.x;
  const long bb = (long)blockIdx.x * EPB;
  const long Q = (long)blockIdx.x * 256 + t;  // global thread id
  const long e0 = Q * (long)EPT;

  // ---- uniform scalar constants (all-lane redundant, cheap)
  const float ae = fabsf(a_exp[0]);
  const float inv_a = 1.0f / fabsf(a_coef[0]);
  float cc0 = fabsf(phi_c[0]), cc1 = fabsf(phi_c[1]);
  float cc2 = fabsf(phi_c[2]), cc3 = fabsf(phi_c[3]);
  {
    float mx = fmaxf(fmaxf(cc0, cc1), fmaxf(cc2, cc3));
    cc0 = expf(cc0 - mx); cc1 = expf(cc1 - mx);
    cc2 = expf(cc2 - mx); cc3 = expf(cc3 - mx);
    float inv_s = 1.0f / (cc0 + cc1 + cc2 + cc3);
    cc0 *= inv_s; cc1 *= inv_s; cc2 *= inv_s; cc3 *= inv_s;
  }
  float q0 = fabsf(phi_e[0]) * LOG2E, q1 = fabsf(phi_e[1]) * LOG2E;
  float q2 = fabsf(phi_e[2]) * LOG2E, q3 = fabsf(phi_e[3]) * LOG2E;
  const float emin = fminf(fminf(q0, q1), fminf(q2, q3));
  // min term gets dd == 0 -> exp2(0) == 1 exactly (matches reference quirk:
  // max_log = -e_min*arg since arg >= 0; shift never added back).
  const float dd0 = (q0 - emin) * inv_a, dd1 = (q1 - emin) * inv_a;
  const float dd2 = (q2 - emin) * inv_a, dd3 = (q3 - emin) * inv_a;

  // ---- phase 1: issue ALL global loads as one flat batch ----
  const int key_base = idx_i[bb];  // uniform broadcast load (cached)
  const int a0 = min(key_base + t, n_atoms - 1);
  const float zw0 = z[a0];          // window stage (coalesced, cached)
  const float am0 = amask[a0];

  int kk0 = -1, kk1 = -1, kk2 = -1, kk3 = -1;
  float dx0 = 0.f, dy0 = 0.f, dz0 = 0.f, bm0 = 0.f, zj0 = 1.f;
  float dx1 = 0.f, dy1 = 0.f, dz1 = 0.f, bm1 = 0.f, zj1 = 1.f;
  float dx2 = 0.f, dy2 = 0.f, dz2 = 0.f, bm2 = 0.f, zj2 = 1.f;
  float dx3 = 0.f, dy3 = 0.f, dz3 = 0.f, bm3 = 0.f, zj3 = 1.f;

  if (e0 + (EPT - 1) < (long)n_edges) {
    // non-temporal streams (zero reuse; keep them out of L2)
    i4v I = __builtin_nontemporal_load(((const i4v*)idx_i) + Q);
    i4v J = __builtin_nontemporal_load(((const i4v*)idx_j) + Q);
    f4v D0 = __builtin_nontemporal_load(((const f4v*)disp) + 3 * Q + 0);
    f4v D1 = __builtin_nontemporal_load(((const f4v*)disp) + 3 * Q + 1);
    f4v D2 = __builtin_nontemporal_load(((const f4v*)disp) + 3 * Q + 2);
    f4v B  = __builtin_nontemporal_load(((const f4v*)bmask) + Q);
    // cached j-gathers (the z table is the only L2-reusable data)
    zj0 = z[I.x >= 0 ? J.x : J.x];  // (no-op select; keeps J live)
    zj0 = z[J.x]; zj1 = z[J.y]; zj2 = z[J.z]; zj3 = z[J.w];
    kk0 = I.x; kk1 = I.y; kk2 = I.z; kk3 = I.w;
    // disp unpack: e0=(D0.x,D0.y,D0.z) e1=(D0.w,D1.x,D1.y)
    //              e2=(D1.z,D1.w,D2.x) e3=(D2.y,D2.z,D2.w)
    dx0 = D0.x; dy0 = D0.y; dz0 = D0.z;
    dx1 = D0.w; dy1 = D1.x; dz1 = D1.y;
    dx2 = D1.z; dy2 = D1.w; dz2 = D2.x;
    dx3 = D2.y; dy3 = D2.z; dz3 = D2.w;
    bm0 = B.x; bm1 = B.y; bm2 = B.z; bm3 = B.w;
  } else {
    long e;
    e = e0;
    if (e < (long)n_edges) {
      kk0 = idx_i[e]; zj0 = z[idx_j[e]];
      dx0 = disp[3 * e]; dy0 = disp[3 * e + 1]; dz0 = disp[3 * e + 2];
      bm0 = bmask[e];
    }
    e = e0 + 1;
    if (e < (long)n_edges) {
      kk1 = idx_i[e]; zj1 = z[idx_j[e]];
      dx1 = disp[3 * e]; dy1 = disp[3 * e + 1]; dz1 = disp[3 * e + 2];
      bm1 = bmask[e];
    }
    e = e0 + 2;
    if (e < (long)n_edges) {
      kk2 = idx_i[e]; zj2 = z[idx_j[e]];
      dx2 = disp[3 * e]; dy2 = disp[3 * e + 1]; dz2 = disp[3 * e + 2];
      bm2 = bmask[e];
    }
    e = e0 + 3;
    if (e < (long)n_edges) {
      kk3 = idx_i[e]; zj3 = z[idx_j[e]];
      dx3 = disp[3 * e]; dy3 = disp[3 * e + 1]; dz3 = disp[3 * e + 2];
      bm3 = bmask[e];
    }
  }

  // ---- LDS stage: za window + acc zero ----
  acc[t] = 0.0f;
  za_s[t] = __builtin_amdgcn_exp2f(ae * __builtin_amdgcn_logf(zw0));
  const float fi0 = 0.5f * zw0 * am0;  // sweep factor (i-side, deferred)
  __syncthreads();

  // ---- phase 2: per-edge values (pure ALU + LDS broadcast reads) ----
  auto edge_val = [&](int kk, float dxv, float dyv, float dzv, float zjv,
                      float bmv) -> float {
    float za_i;
    {
      int s = kk - key_base;
      if ((unsigned)s < (unsigned)NSLOT) za_i = za_s[s];
      else if (kk >= 0)  // out-of-window fallback (unsorted pathological)
        za_i = __builtin_amdgcn_exp2f(ae * __builtin_amdgcn_logf(z[kk]));
      else return 0.0f;
    }
    float n2 = fmaxf(dxv * dxv + dyv * dyv + dzv * dzv, 1e-20f);
    float r = __builtin_amdgcn_rsqf(n2);  // 1/d
    float d = n2 * r;                     // d = sqrt(n2)
    float x = 5.0f - d;
    float poly = ((6.0f * x - 15.0f) * x + 10.0f) * x * x * x;
    float sw = (d < 4.0f) ? 1.0f : ((d >= 5.0f) ? 0.0f : poly);
    float zaj = __builtin_amdgcn_exp2f(ae * __builtin_amdgcn_logf(zjv));
    float qq = d * fmaxf(za_i + zaj, 1e-10f);
    float phi = cc0 * __builtin_amdgcn_exp2f(-dd0 * qq)
              + cc1 * __builtin_amdgcn_exp2f(-dd1 * qq)
              + cc2 * __builtin_amdgcn_exp2f(-dd2 * qq)
              + cc3 * __builtin_amdgcn_exp2f(-dd3 * qq);
    // i-factor (0.5*z_i*amask_i) deferred to sweep
    return zjv * r * fmaxf(phi, 1e-30f) * fmaxf(sw, 1e-30f) * bmv;
  };

  const float v0 = edge_val(kk0, dx0, dy0, dz0, zj0, bm0);
  const float v1 = edge_val(kk1, dx1, dy1, dz1, zj1, bm1);
  const float v2 = edge_val(kk2, dx2, dy2, dz2, zj2, bm2);
  const float v3 = edge_val(kk3, dx3, dy3, dz3, zj3, bm3);

  auto flush = [&](int key, float s) {
    if (key < 0) return;
    int slot = key - key_base;
    if ((unsigned)slot < (unsigned)NSLOT) {
      atomicAdd(&acc[slot], s);
    } else {  // rare fallback: apply i-factor directly
      atomicAdd(&out[key], s * 0.5f * z[key] * amask[key]);
    }
  };

  // ---- in-register merge of equal-adjacent keys ----
  {
    int cur = kk0;
    float s = v0;
    if (kk1 == cur) s += v1; else { flush(cur, s); cur = kk1; s = v1; }
    if (kk2 == cur) s += v2; else { flush(cur, s); cur = kk2; s = v2; }
    if (kk3 == cur) s += v3; else { flush(cur, s); cur = kk3; s = v3; }
    flush(cur, s);
  }

  __syncthreads();  // all LDS accumulation done

  // ---- sweep: one global atomic per touched atom ----
  {
    float val = acc[t];
    if (val != 0.0f) atomicAdd(&out[key_base + t], val * fi0);
  }
}

extern "C" void kernel_launch(void* const* d_in, const int* in_sizes, int n_in,
                              void* d_out, int out_size, void* d_ws,
                              size_t ws_size, hipStream_t stream) {
  const float* atomic_numbers = (const float*)d_in[0];
  const float* disp           = (const float*)d_in[1];
  const int*   idx_i          = (const int*)d_in[2];
  const int*   idx_j          = (const int*)d_in[3];
  const float* atom_mask      = (const float*)d_in[4];
  // d_in[5] = batch_segments (unused), d_in[7] = batch_size (unused)
  const float* bmask          = (const float*)d_in[6];
  const float* a_coef         = (const float*)d_in[8];
  const float* a_exp          = (const float*)d_in[9];
  const float* phi_c          = (const float*)d_in[10];
  const float* phi_e          = (const float*)d_in[11];

  int n_atoms = in_sizes[0];
  int n_edges = in_sizes[2];

  float* out = (float*)d_out;

  hipMemsetAsync(out, 0, (size_t)out_size * sizeof(float), stream);

  int edge_blocks = (int)(((long)n_edges + EPB - 1) / EPB);
  zbl_fused_kernel<<<edge_blocks, 256, 0, stream>>>(
      atomic_numbers, atom_mask, disp, idx_i, idx_j, bmask, a_coef, a_exp,
      phi_c, phi_e, out, n_edges, n_atoms);
}

// Round 11
// 47.474 us; speedup vs baseline: 1.3082x; 1.3082x over previous
//
#include <hip/hip_runtime.h>
#include <math.h>

#define LOG2E 1.4426950408889634f
#define NSLOT 512   // LDS accumulator slots per block (block spans ~16 atoms)
#define EPB   1024  // edges per block (256 threads x 4 edges)

// consts layout (7 floats):
//   [0]    softmax coeff of the min-exponent term (its exp factor == 1)
//   [1..3] softmax coeffs of the other 3 terms
//   [4..6] (e2_k - e2_min) / |a|   (log2-domain exponent deltas, pre-divided)

// ---------------------------------------------------------------------------
// Kernel 1: per-atom table (z, z^|a_exp|), zero output, scalar consts.
// ---------------------------------------------------------------------------
__global__ __launch_bounds__(256) void zbl_prep_kernel(
    const float* __restrict__ z, const float* __restrict__ a_coef,
    const float* __restrict__ a_exp, const float* __restrict__ phi_c,
    const float* __restrict__ phi_e, float2* __restrict__ tab,
    float* __restrict__ out, float* __restrict__ consts, int n_atoms) {
  int n = blockIdx.x * blockDim.x + threadIdx.x;
  if (n < n_atoms) {
    float zi = z[n];                       // in [1, 94] -> log safe
    float ae = fabsf(a_exp[0]);
    float za = __builtin_amdgcn_exp2f(ae * __builtin_amdgcn_logf(zi));
    tab[n] = make_float2(zi, za);
    out[n] = 0.0f;
  }
  if (blockIdx.x == 0 && threadIdx.x == 0) {
    float c[4], e2[4];
    float m = -1e30f;
    for (int k = 0; k < 4; ++k) { c[k] = fabsf(phi_c[k]); m = fmaxf(m, c[k]); }
    float s = 0.0f;
    for (int k = 0; k < 4; ++k) { c[k] = expf(c[k] - m); s += c[k]; }
    for (int k = 0; k < 4; ++k) c[k] /= s;
    int kmin = 0;
    for (int k = 0; k < 4; ++k) {
      e2[k] = fabsf(phi_e[k]) * LOG2E;
      if (e2[k] < e2[kmin]) kmin = k;
    }
    float inv_a = 1.0f / fabsf(a_coef[0]);
    consts[0] = c[kmin];
    int p = 1;
    for (int k = 0; k < 4; ++k) {
      if (k != kmin) {
        consts[p] = c[k];
        consts[3 + p] = (e2[k] - e2[kmin]) * inv_a;
        ++p;
      }
    }
  }
}

// ---------------------------------------------------------------------------
// Per-edge math (verified in R3): rep value + segment key.
// ---------------------------------------------------------------------------
__device__ __forceinline__ void zbl_edge_compute(
    float dx, float dy, float dz, int i, int j, float bm,
    const float2* __restrict__ tab, float c0, float c1, float c2, float c3,
    float dd1, float dd2, float dd3, int& kk, float& vv) {
  float n2 = fmaxf(dx * dx + dy * dy + dz * dz, 1e-20f);
  float r = __builtin_amdgcn_rsqf(n2);  // 1/d
  float d = n2 * r;                     // d = sqrt(n2)
  // smooth switch on [CUTON=4, CUTOFF=5]
  float x = 5.0f - d;
  float poly = ((6.0f * x - 15.0f) * x + 10.0f) * x * x * x;
  float sw = (d < 4.0f) ? 1.0f : ((d >= 5.0f) ? 0.0f : poly);
  float2 ti = tab[i];
  float2 tj = tab[j];
  float q = d * fmaxf(ti.y + tj.y, 1e-10f);
  // phi = c_min + sum_k c_k * 2^(-dd_k*q)  (reference's shifted-exp quirk:
  // max_log = -e_min*arg is always the max term since arg >= 0)
  float phi = c0 + c1 * __builtin_amdgcn_exp2f(-dd1 * q)
                 + c2 * __builtin_amdgcn_exp2f(-dd2 * q)
                 + c3 * __builtin_amdgcn_exp2f(-dd3 * q);
  vv = 0.5f * ti.x * tj.x * r * fmaxf(phi, 1e-30f) * fmaxf(sw, 1e-30f) * bm;
  kk = i;
}

// ---------------------------------------------------------------------------
// Kernel 2: block owns 1024 consecutive edges (4/thread, vectorized loads).
// In-register run merge -> LDS float atomics into slots keyed relative to the
// block's first atom (sorted idx_i => span ~16 atoms) -> barrier -> sweep
// slots, one global atomic per touched atom with atom_mask folded in.
// Out-of-range keys (unsorted/pathological) fall back to global atomics, so
// correctness never depends on sortedness.
// ---------------------------------------------------------------------------
__global__ __launch_bounds__(256) void zbl_edge_kernel(
    const float* __restrict__ disp, const int* __restrict__ idx_i,
    const int* __restrict__ idx_j, const float* __restrict__ bmask,
    const float2* __restrict__ tab, const float* __restrict__ consts,
    const float* __restrict__ amask, float* __restrict__ out, int n_edges) {
  __shared__ float acc[NSLOT];
  const int t = threadIdx.x;
  const long block_base = (long)blockIdx.x * EPB;

  acc[t] = 0.0f;
  acc[t + 256] = 0.0f;

  const int key_base = idx_i[block_base];  // uniform broadcast load
  const float c0 = consts[0], c1 = consts[1], c2 = consts[2], c3 = consts[3];
  const float dd1 = consts[4], dd2 = consts[5], dd3 = consts[6];

  const long L = (long)blockIdx.x * 256 + t;  // global quad id
  const long e0 = L * 4;

  int k[4] = {-1, -1, -1, -1};
  float v[4] = {0.f, 0.f, 0.f, 0.f};

  if (e0 + 3 < (long)n_edges) {
    const float4* d4 = (const float4*)disp;
    float4 A = d4[3 * L], B = d4[3 * L + 1], Cc = d4[3 * L + 2];
    int4 I = ((const int4*)idx_i)[L];
    int4 J = ((const int4*)idx_j)[L];
    float4 BM = ((const float4*)bmask)[L];
    // disp unpack: e0=(A.x,A.y,A.z) e1=(A.w,B.x,B.y) e2=(B.z,B.w,Cc.x)
    //              e3=(Cc.y,Cc.z,Cc.w)
    zbl_edge_compute(A.x, A.y, A.z, I.x, J.x, BM.x, tab, c0, c1, c2, c3, dd1, dd2, dd3, k[0], v[0]);
    zbl_edge_compute(A.w, B.x, B.y, I.y, J.y, BM.y, tab, c0, c1, c2, c3, dd1, dd2, dd3, k[1], v[1]);
    zbl_edge_compute(B.z, B.w, Cc.x, I.z, J.z, BM.z, tab, c0, c1, c2, c3, dd1, dd2, dd3, k[2], v[2]);
    zbl_edge_compute(Cc.y, Cc.z, Cc.w, I.w, J.w, BM.w, tab, c0, c1, c2, c3, dd1, dd2, dd3, k[3], v[3]);
  } else {
    #pragma unroll
    for (int m = 0; m < 4; ++m) {
      const long e = e0 + m;
      if (e < (long)n_edges)
        zbl_edge_compute(disp[3 * e], disp[3 * e + 1], disp[3 * e + 2],
                         idx_i[e], idx_j[e], bmask[e], tab, c0, c1, c2, c3,
                         dd1, dd2, dd3, k[m], v[m]);
    }
  }

  __syncthreads();  // LDS zeroing complete before any atomics land

  auto flush = [&](int key, float s) {
    if (key < 0) return;
    int slot = key - key_base;
    if ((unsigned)slot < (unsigned)NSLOT) atomicAdd(&acc[slot], s);
    else atomicAdd(&out[key], s * amask[key]);
  };

  // in-register merge of equal-adjacent keys (sorted => ~1 run per thread)
  int cur = k[0];
  float s = v[0];
  #pragma unroll
  for (int m = 1; m < 4; ++m) {
    if (k[m] == cur) {
      s += v[m];
    } else {
      flush(cur, s);
      cur = k[m];
      s = v[m];
    }
  }
  flush(cur, s);

  __syncthreads();  // all LDS accumulation done

  #pragma unroll
  for (int s2 = 0; s2 < NSLOT; s2 += 256) {
    float val = acc[t + s2];
    if (val != 0.0f) {  // zero-valued slots contribute nothing; skip is exact
      int a = key_base + t + s2;
      atomicAdd(&out[a], val * amask[a]);
    }
  }
}

extern "C" void kernel_launch(void* const* d_in, const int* in_sizes, int n_in,
                              void* d_out, int out_size, void* d_ws,
                              size_t ws_size, hipStream_t stream) {
  const float* atomic_numbers = (const float*)d_in[0];
  const float* disp           = (const float*)d_in[1];
  const int*   idx_i          = (const int*)d_in[2];
  const int*   idx_j          = (const int*)d_in[3];
  const float* atom_mask      = (const float*)d_in[4];
  // d_in[5] = batch_segments (unused), d_in[7] = batch_size (unused)
  const float* bmask          = (const float*)d_in[6];
  const float* a_coef         = (const float*)d_in[8];
  const float* a_exp          = (const float*)d_in[9];
  const float* phi_c          = (const float*)d_in[10];
  const float* phi_e          = (const float*)d_in[11];

  int n_atoms = in_sizes[0];
  int n_edges = in_sizes[2];

  float* out = (float*)d_out;
  float2* tab = (float2*)d_ws;
  float* consts = (float*)((char*)d_ws + (size_t)n_atoms * sizeof(float2));

  int atom_blocks = (n_atoms + 255) / 256;
  int edge_blocks = (int)(((long)n_edges + EPB - 1) / EPB);

  zbl_prep_kernel<<<atom_blocks, 256, 0, stream>>>(
      atomic_numbers, a_coef, a_exp, phi_c, phi_e, tab, out, consts, n_atoms);
  zbl_edge_kernel<<<edge_blocks, 256, 0, stream>>>(
      disp, idx_i, idx_j, bmask, tab, consts, atom_mask, out, n_edges);
}